// Round 4
// baseline (767.345 us; speedup 1.0000x reference)
//
#include <hip/hip_runtime.h>

#define NN 4096
#define HH 32
#define DD 128
#define MM 16
#define PP 8192

__device__ __forceinline__ float4 ld4(const float* p) { return *(const float4*)(p); }
__device__ __forceinline__ float dot4f(float4 a, float4 b) {
  return a.x * b.x + a.y * b.y + a.z * b.z + a.w * b.w;
}

// ---------------------------------------------------------------- K1: RMS inv
__global__ void k1_rms(const float* __restrict__ X, float* __restrict__ inv) {
  const int m = blockIdx.x;
  const int tid = threadIdx.x;
  float s = 0.f;
#pragma unroll
  for (int i = 0; i < 16; ++i) {
    float v = X[(size_t)m * NN + i * 256 + tid];
    s += v * v;
  }
#pragma unroll
  for (int off = 1; off < 64; off <<= 1) s += __shfl_xor(s, off, 64);
  __shared__ float red[4];
  if ((tid & 63) == 0) red[tid >> 6] = s;
  __syncthreads();
  if (tid == 0) {
    float t = red[0] + red[1] + red[2] + red[3];
    inv[m] = rsqrtf(t * (1.0f / (float)NN));
  }
}

// ------------------------------------------------- K2: QKV k-window partials
// grid 768 = 3 mats x 16 k-windows x 16 row-blocks. block 256 = 4 waves.
// Wave owns 64 rows x one 256-float k-window. NO LDS, NO barriers.
// lane=(m4,g16): X[4 m][16 k] in regs; W streamed coalesced, register
// double-buffered 2-row batches; 8-shfl scatter-reduce -> coalesced store.
__global__ __launch_bounds__(256, 3) void k2_qkv(
    const float* __restrict__ X, const float* __restrict__ Wq,
    const float* __restrict__ Wk, const float* __restrict__ Wv,
    float* __restrict__ c_part) {
  const int b = blockIdx.x;
  const int mat = b >> 8;
  const int rem = b & 255;
  const int kw = rem >> 4;
  const int rblk = rem & 15;
  const float* W = (mat == 0) ? Wq : (mat == 1) ? Wk : Wv;
  const int tid = threadIdx.x;
  const int wave = tid >> 6;
  const int lane = tid & 63;
  const int m4 = lane & 3;
  const int g = lane >> 2;
  const int r0 = rblk * 256 + wave * 64;
  const int koff = kw * 256 + g * 16;

  // X fragments: xr[mi][j] = X[mi*4+m4][koff + j*4 ..]
  float4 xr[4][4];
#pragma unroll
  for (int mi = 0; mi < 4; ++mi) {
    const float* xp = X + (size_t)(mi * 4 + m4) * NN + koff;
#pragma unroll
    for (int j = 0; j < 4; ++j) xr[mi][j] = ld4(xp + j * 4);
  }

  const float* Wb = W + (size_t)r0 * NN + koff;
  const size_t cb = ((size_t)(mat * 16 + kw)) * 65536;  // [mat][kw][4096 rows][16 m]

  float4 wb[2][2][4];  // [phase][row-in-batch][chunk]
#pragma unroll
  for (int r = 0; r < 2; ++r) {
    const float* wr = Wb + (size_t)r * NN;
#pragma unroll
    for (int j = 0; j < 4; ++j) wb[0][r][j] = ld4(wr + j * 4);
  }

  for (int bt = 0; bt < 32; ++bt) {
    const int ph = bt & 1;
    if (bt < 31) {
#pragma unroll
      for (int r = 0; r < 2; ++r) {
        const float* wr = Wb + (size_t)((bt + 1) * 2 + r) * NN;
#pragma unroll
        for (int j = 0; j < 4; ++j) wb[ph ^ 1][r][j] = ld4(wr + j * 4);
      }
    }
    float v[8];  // index r*4+mi
#pragma unroll
    for (int i = 0; i < 8; ++i) v[i] = 0.f;
#pragma unroll
    for (int r = 0; r < 2; ++r)
#pragma unroll
      for (int j = 0; j < 4; ++j)
#pragma unroll
        for (int mi = 0; mi < 4; ++mi)
          v[r * 4 + mi] += dot4f(xr[mi][j], wb[ph][r][j]);
    // scatter-reduce 8 values over the 16 g-lanes (g bits = lane bits 2..5)
    {
      const bool u32 = (lane & 32) != 0;
#pragma unroll
      for (int i = 0; i < 4; ++i) {
        float send = u32 ? v[i] : v[i + 4];
        float recv = __shfl_xor(send, 32, 64);
        v[i] = (u32 ? v[i + 4] : v[i]) + recv;
      }
      const bool u16 = (lane & 16) != 0;
#pragma unroll
      for (int i = 0; i < 2; ++i) {
        float send = u16 ? v[i] : v[i + 2];
        float recv = __shfl_xor(send, 16, 64);
        v[i] = (u16 ? v[i + 2] : v[i]) + recv;
      }
      const bool u8 = (lane & 8) != 0;
      {
        float send = u8 ? v[0] : v[1];
        float recv = __shfl_xor(send, 8, 64);
        v[0] = (u8 ? v[1] : v[0]) + recv;
      }
      v[0] += __shfl_xor(v[0], 4, 64);
    }
    // lane holds value for r = (g>>3), mi = (g>>1)&3, m = mi*4+m4
    if (!(lane & 4)) {
      const int row = r0 + bt * 2 + (g >> 3);
      const int m = ((g >> 1) & 3) * 4 + m4;
      c_part[cb + (size_t)row * 16 + m] = v[0];
    }
  }
}

// --------------------------------------- K2b: combine k-windows, scale by inv
// qkv[mat][m][j] = inv[m] * sum_kw c_part[mat][kw][j][m]
__global__ void k2b_combine(const float* __restrict__ c_part,
                            const float* __restrict__ inv,
                            float* __restrict__ qkv) {
  const int t = blockIdx.x * 256 + threadIdx.x;  // 0..196607
  const int mat = t >> 16;
  const int r = t & 65535;
  const int m = r >> 12;
  const int j = r & 4095;
  float s = 0.f;
#pragma unroll
  for (int kw = 0; kw < 16; ++kw)
    s += c_part[((size_t)(mat * 16 + kw)) * 65536 + (size_t)j * 16 + m];
  qkv[(((size_t)(mat * 16 + m)) << 12) + j] = s * inv[m];
}

// ------------------------------------------------- K3: attention partials
// grid 512 = 32 h x 16 seg. Wave owns 128 contiguous p. NO LDS, NO barriers.
// K/V streamed direct from global, register double-buffered (depth 2 p).
// lane=(m8,g8): 2 m x 16 d; 3-stage shuffle reduce; per-wave partial out.
__global__ __launch_bounds__(256, 2) void k3_attn(
    const float* __restrict__ cK, const float* __restrict__ cV,
    const float* __restrict__ qkv, float* __restrict__ o_part,
    float* __restrict__ den_part) {
  const int b = blockIdx.x;
  const int h = b >> 4;
  const int seg = b & 15;
  const int tid = threadIdx.x;
  const int wave = tid >> 6;
  const int lane = tid & 63;
  const int m8 = lane & 7;
  const int g = lane >> 3;
  const int d0 = g * 16;

  float4 q0[4], q1[4];
  {
    const float* qa = qkv + (size_t)m8 * NN + h * DD + d0;
    const float* qb = qkv + (size_t)(m8 + 8) * NN + h * DD + d0;
#pragma unroll
    for (int j = 0; j < 4; ++j) { q0[j] = ld4(qa + j * 4); q1[j] = ld4(qb + j * 4); }
  }
  float o0[16], o1[16];
#pragma unroll
  for (int j = 0; j < 16; ++j) { o0[j] = 0.f; o1[j] = 0.f; }
  float den0 = 0.f, den1 = 0.f;

  const size_t rowb = ((size_t)h * PP + seg * 512 + wave * 128) * DD;
  const float* kb = cK + rowb + d0;
  const float* vb = cV + rowb + d0;

  float4 kA[4], vA[4], kB[4], vB[4];
#pragma unroll
  for (int j = 0; j < 4; ++j) { kA[j] = ld4(kb + j * 4); vA[j] = ld4(vb + j * 4); }

#define K3_COMPUTE(KR, VR)                                                     \
  {                                                                            \
    float c0 = dot4f(q0[0], KR[0]) + dot4f(q0[1], KR[1]) +                     \
               dot4f(q0[2], KR[2]) + dot4f(q0[3], KR[3]);                      \
    float c1 = dot4f(q1[0], KR[0]) + dot4f(q1[1], KR[1]) +                     \
               dot4f(q1[2], KR[2]) + dot4f(q1[3], KR[3]);                      \
    c0 += __shfl_xor(c0, 8, 64);  c1 += __shfl_xor(c1, 8, 64);                 \
    c0 += __shfl_xor(c0, 16, 64); c1 += __shfl_xor(c1, 16, 64);                \
    c0 += __shfl_xor(c0, 32, 64); c1 += __shfl_xor(c1, 32, 64);                \
    float e0 = __expf(c0), e1 = __expf(c1);                                    \
    den0 += e0; den1 += e1;                                                    \
    o0[0] += e0 * VR[0].x;  o0[1] += e0 * VR[0].y;                             \
    o0[2] += e0 * VR[0].z;  o0[3] += e0 * VR[0].w;                             \
    o0[4] += e0 * VR[1].x;  o0[5] += e0 * VR[1].y;                             \
    o0[6] += e0 * VR[1].z;  o0[7] += e0 * VR[1].w;                             \
    o0[8] += e0 * VR[2].x;  o0[9] += e0 * VR[2].y;                             \
    o0[10] += e0 * VR[2].z; o0[11] += e0 * VR[2].w;                            \
    o0[12] += e0 * VR[3].x; o0[13] += e0 * VR[3].y;                            \
    o0[14] += e0 * VR[3].z; o0[15] += e0 * VR[3].w;                            \
    o1[0] += e1 * VR[0].x;  o1[1] += e1 * VR[0].y;                             \
    o1[2] += e1 * VR[0].z;  o1[3] += e1 * VR[0].w;                             \
    o1[4] += e1 * VR[1].x;  o1[5] += e1 * VR[1].y;                             \
    o1[6] += e1 * VR[1].z;  o1[7] += e1 * VR[1].w;                             \
    o1[8] += e1 * VR[2].x;  o1[9] += e1 * VR[2].y;                             \
    o1[10] += e1 * VR[2].z; o1[11] += e1 * VR[2].w;                            \
    o1[12] += e1 * VR[3].x; o1[13] += e1 * VR[3].y;                            \
    o1[14] += e1 * VR[3].z; o1[15] += e1 * VR[3].w;                            \
  }

  for (int pi = 0; pi < 128; pi += 2) {
    const float* kn = kb + (size_t)(pi + 1) * DD;
    const float* vn = vb + (size_t)(pi + 1) * DD;
#pragma unroll
    for (int j = 0; j < 4; ++j) { kB[j] = ld4(kn + j * 4); vB[j] = ld4(vn + j * 4); }
    K3_COMPUTE(kA, vA)
    if (pi + 2 < 128) {
      const float* kn2 = kb + (size_t)(pi + 2) * DD;
      const float* vn2 = vb + (size_t)(pi + 2) * DD;
#pragma unroll
      for (int j = 0; j < 4; ++j) { kA[j] = ld4(kn2 + j * 4); vA[j] = ld4(vn2 + j * 4); }
    }
    K3_COMPUTE(kB, vB)
  }

  // appended 16 rows (k = qkv mat1, v = qkv mat2): one block per head
  if (seg == (h & 15)) {
#pragma unroll
    for (int pi = 0; pi < 4; ++pi) {
      const int p = wave * 4 + pi;
      const float* kp = qkv + (size_t)(16 + p) * NN + h * DD + d0;
      const float* vp = qkv + (size_t)(32 + p) * NN + h * DD + d0;
      float4 kr[4], vr[4];
#pragma unroll
      for (int j = 0; j < 4; ++j) { kr[j] = ld4(kp + j * 4); vr[j] = ld4(vp + j * 4); }
      K3_COMPUTE(kr, vr)
    }
  }
#undef K3_COMPUTE

  // write per-wave partials
  float* op = o_part + ((size_t)b * 4 + wave) * 2048;
#pragma unroll
  for (int j = 0; j < 4; ++j) {
    *(float4*)(op + m8 * DD + d0 + j * 4) =
        make_float4(o0[j * 4], o0[j * 4 + 1], o0[j * 4 + 2], o0[j * 4 + 3]);
    *(float4*)(op + (m8 + 8) * DD + d0 + j * 4) =
        make_float4(o1[j * 4], o1[j * 4 + 1], o1[j * 4 + 2], o1[j * 4 + 3]);
  }
  if (g == 0) {
    den_part[((size_t)b * 4 + wave) * 16 + m8] = den0;
    den_part[((size_t)b * 4 + wave) * 16 + 8 + m8] = den1;
  }
}

// -------------------------------------------------------- K4: final reduce
// grid 256 = 32 h x 8 sub; sum 64 wave-partials per head, divide, write out.
__global__ void k4_final(const float* __restrict__ o_part,
                         const float* __restrict__ den_part,
                         float* __restrict__ out) {
  const int b = blockIdx.x;
  const int h = b >> 3;
  const int tid = threadIdx.x;
  const int idx = (b & 7) * 256 + tid;  // 0..2047 = m*128+d
  __shared__ float dinv[16];
  if (tid < 16) {
    float s = 0.f;
    for (int j = 0; j < 64; ++j) s += den_part[(size_t)h * 1024 + j * 16 + tid];
    dinv[tid] = 1.0f / s;
  }
  __syncthreads();
  float s = 0.f;
  for (int j = 0; j < 64; ++j) s += o_part[(size_t)h * 131072 + j * 2048 + idx];
  const int m = idx >> 7;
  const int d = idx & 127;
  out[(size_t)m * NN + h * DD + d] = s * dinv[m];
}

extern "C" void kernel_launch(void* const* d_in, const int* in_sizes, int n_in,
                              void* d_out, int out_size, void* d_ws, size_t ws_size,
                              hipStream_t stream) {
  (void)in_sizes; (void)n_in; (void)out_size; (void)ws_size;
  const float* X  = (const float*)d_in[0];
  const float* Wq = (const float*)d_in[1];
  const float* Wk = (const float*)d_in[2];
  const float* Wv = (const float*)d_in[3];
  const float* cK = (const float*)d_in[4];
  const float* cV = (const float*)d_in[5];
  float* out = (float*)d_out;
  float* ws = (float*)d_ws;

  float* inv      = ws;                  // 16
  float* c_part   = ws + 16;             // 3*16*4096*16 = 3145728
  float* qkv      = c_part + 3145728;    // 3*16*4096    = 196608
  float* o_part   = qkv + 196608;        // 512*4*2048   = 4194304
  float* den_part = o_part + 4194304;    // 512*4*16     = 32768
  // total ~30.3 MB

  k1_rms<<<16, 256, 0, stream>>>(X, inv);
  k2_qkv<<<768, 256, 0, stream>>>(X, Wq, Wk, Wv, c_part);
  k2b_combine<<<768, 256, 0, stream>>>(c_part, inv, qkv);
  k3_attn<<<512, 256, 0, stream>>>(cK, cV, qkv, o_part, den_part);
  k4_final<<<256, 256, 0, stream>>>(o_part, den_part, out);
}